// Round 1
// baseline (39365.948 us; speedup 1.0000x reference)
//
#include <hip/hip_runtime.h>

#define B_SZ 512
#define SEQ 96
#define PRED 48
#define TOT 144
#define CIN 7
#define DM 128
#define GDIM 384
#define KS 5

#define CSTR 132      // LDS row stride for conv buffers (16B-aligned, conflict-safe)
#define GXS 388       // LDS row stride for gx chunk

#define W_CONV (KS*DM*DM)          // 81920 per conv layer (layout [k][c][o])
#define OFF_WIT (3*W_CONV)         // WiT [c][384]
#define OFF_WHT (3*W_CONV + DM*GDIM) // WhT [c][384]
#define W_TOTAL (3*W_CONV + 2*DM*GDIM)

// Device-global scratch (avoids any dependence on ws_size)
__device__ float g_c3[B_SZ*SEQ*DM];     // conv3 output, [b][t][128]
__device__ float g_wT[W_TOTAL];         // transposed weights

// ---------------------------------------------------------------- prep
__global__ void prep_weights(const float* __restrict__ w1, const float* __restrict__ w2,
                             const float* __restrict__ w3, const float* __restrict__ Wi,
                             const float* __restrict__ Wh) {
    int tid = blockIdx.x*256 + threadIdx.x;
    if (tid < 3*W_CONV) {
        int l = tid / W_CONV, r = tid % W_CONV;
        int o = r & 127, c = (r >> 7) & 127, k = r >> 14;   // r = (k*128+c)*128+o
        const float* w = (l==0) ? w1 : ((l==1) ? w2 : w3);
        g_wT[tid] = w[o*(DM*KS) + c*KS + k];                 // src [o][c][k]
    } else if (tid < W_TOTAL) {
        int r = tid - 3*W_CONV;
        int m = r / (DM*GDIM), q = r % (DM*GDIM);
        int g = q % GDIM, c = q / GDIM;                      // dst [c][g]
        const float* W = (m==0) ? Wi : Wh;
        g_wT[tid] = W[g*DM + c];                             // src [g][c]
    }
}

// 8-wide FMA helper
__device__ __forceinline__ void fma8(float (&acc)[4][8], int j, float a,
                                     const float4& wA, const float4& wB) {
    acc[j][0] = fmaf(a, wA.x, acc[j][0]);
    acc[j][1] = fmaf(a, wA.y, acc[j][1]);
    acc[j][2] = fmaf(a, wA.z, acc[j][2]);
    acc[j][3] = fmaf(a, wA.w, acc[j][3]);
    acc[j][4] = fmaf(a, wB.x, acc[j][4]);
    acc[j][5] = fmaf(a, wB.y, acc[j][5]);
    acc[j][6] = fmaf(a, wB.z, acc[j][6]);
    acc[j][7] = fmaf(a, wB.w, acc[j][7]);
}

// One LDS->LDS conv layer. IN rows [0,nttg*4+4); OUT rows [0,nttg*4); out row q
// corresponds to window row winO+q, masked to zero outside [0,SEQ).
__device__ __forceinline__ void conv_lds(const float* __restrict__ IN, float* __restrict__ OUT,
                                         const float* __restrict__ wT,
                                         const float* __restrict__ bias,
                                         int nttg, int winO, int tid) {
    const int og = tid & 15, ttg = tid >> 4;
    if (ttg >= nttg) return;
    const int o0 = og*8, r0 = ttg*4;
    float acc[4][8];
    #pragma unroll
    for (int u = 0; u < 8; ++u) {
        float bv = bias[o0+u];
        #pragma unroll
        for (int j = 0; j < 4; ++j) acc[j][u] = bv;
    }
    for (int c = 0; c < DM; c += 2) {
        float2 a2[8];
        #pragma unroll
        for (int m = 0; m < 8; ++m)
            a2[m] = *(const float2*)(IN + (r0+m)*CSTR + c);
        #pragma unroll
        for (int k = 0; k < KS; ++k) {
            const float4 wA0 = *(const float4*)(wT + (k*DM + c)*DM + o0);
            const float4 wB0 = *(const float4*)(wT + (k*DM + c)*DM + o0 + 4);
            const float4 wA1 = *(const float4*)(wT + (k*DM + c+1)*DM + o0);
            const float4 wB1 = *(const float4*)(wT + (k*DM + c+1)*DM + o0 + 4);
            #pragma unroll
            for (int j = 0; j < 4; ++j) {
                fma8(acc, j, a2[j+k].x, wA0, wB0);
                fma8(acc, j, a2[j+k].y, wA1, wB1);
            }
        }
    }
    #pragma unroll
    for (int j = 0; j < 4; ++j) {
        int q = r0 + j, w = winO + q;
        bool valid = (w >= 0) && (w < SEQ);
        #pragma unroll
        for (int u = 0; u < 8; ++u)
            OUT[q*CSTR + o0+u] = valid ? fmaxf(acc[j][u], 0.f) : 0.f;
    }
}

// ------------------------------------------------------------- conv kernel
// grid (512, 2): b = blockIdx.x, chunk cs = 48*blockIdx.y. Computes c3 for
// window rows [cs, cs+48) of step i.
__launch_bounds__(256)
__global__ void conv_kernel(int i, const float* __restrict__ x_enc,
                            const int* __restrict__ y_mark,
                            const float* __restrict__ hour_e, const float* __restrict__ wk_e,
                            const float* __restrict__ day_e, const float* __restrict__ mon_e,
                            const float* __restrict__ W_val, const float* __restrict__ b_val,
                            const float* __restrict__ b1, const float* __restrict__ b2,
                            const float* __restrict__ b3, const float* __restrict__ out) {
    __shared__ float bufI[60*CSTR];
    __shared__ float bufO[56*CSTR];
    const int tid = threadIdx.x;
    const int b = blockIdx.x;
    const int cs = blockIdx.y * 48;

    // ---- embedding: rows q=0..59 -> window row w = cs-6+q (zero outside [0,96))
    for (int e = tid; e < 60*DM; e += 256) {
        int q = e >> 7, d = e & 127;
        int w = cs - 6 + q;
        float v = 0.f;
        if (w >= 0 && w < SEQ) {
            int p = i + w;
            const float* xr = (p < SEQ) ? (x_enc + (b*SEQ + p)*CIN)
                                        : (out + (b*PRED + (p - SEQ))*CIN);
            v = b_val[d];
            #pragma unroll
            for (int c = 0; c < CIN; ++c) v = fmaf(xr[c], W_val[d*CIN + c], v);
            const int* ym = y_mark + (b*TOT + p)*4;
            v += hour_e[ym[0]*DM + d] + wk_e[ym[1]*DM + d]
               + day_e[ym[2]*DM + d] + mon_e[ym[3]*DM + d];
        }
        bufI[q*CSTR + d] = v;
    }
    __syncthreads();
    conv_lds(bufI, bufO, g_wT,            b1, 14, cs - 4, tid);  // c1: 56 rows
    __syncthreads();
    conv_lds(bufO, bufI, g_wT + W_CONV,   b2, 13, cs - 2, tid);  // c2: 52 rows
    __syncthreads();
    // ---- c3 -> global (48 rows, all valid)
    {
        const int og = tid & 15, ttg = tid >> 4;
        if (ttg < 12) {
            const int o0 = og*8, r0 = ttg*4;
            const float* wT = g_wT + 2*W_CONV;
            float acc[4][8];
            #pragma unroll
            for (int u = 0; u < 8; ++u) {
                float bv = b3[o0+u];
                #pragma unroll
                for (int j = 0; j < 4; ++j) acc[j][u] = bv;
            }
            for (int c = 0; c < DM; c += 2) {
                float2 a2[8];
                #pragma unroll
                for (int m = 0; m < 8; ++m)
                    a2[m] = *(const float2*)(bufI + (r0+m)*CSTR + c);
                #pragma unroll
                for (int k = 0; k < KS; ++k) {
                    const float4 wA0 = *(const float4*)(wT + (k*DM + c)*DM + o0);
                    const float4 wB0 = *(const float4*)(wT + (k*DM + c)*DM + o0 + 4);
                    const float4 wA1 = *(const float4*)(wT + (k*DM + c+1)*DM + o0);
                    const float4 wB1 = *(const float4*)(wT + (k*DM + c+1)*DM + o0 + 4);
                    #pragma unroll
                    for (int j = 0; j < 4; ++j) {
                        fma8(acc, j, a2[j+k].x, wA0, wB0);
                        fma8(acc, j, a2[j+k].y, wA1, wB1);
                    }
                }
            }
            #pragma unroll
            for (int j = 0; j < 4; ++j) {
                int t = cs + r0 + j;
                #pragma unroll
                for (int u = 0; u < 8; ++u)
                    g_c3[(b*SEQ + t)*DM + o0+u] = fmaxf(acc[j][u], 0.f);
            }
        }
    }
}

// -------------------------------------------------------------- GRU kernel
// grid 512 (one batch row per block), 384 threads (thread = gate g).
__launch_bounds__(GDIM)
__global__ void gru_kernel(int i, const float* __restrict__ gbi, const float* __restrict__ gbh,
                           const float* __restrict__ fc_w, const float* __restrict__ fc_b,
                           float* __restrict__ out) {
    __shared__ float gx[32*GXS];
    __shared__ float H[DM];
    __shared__ float GS[2*DM];
    const int tid = threadIdx.x;
    const int b = blockIdx.x;
    const float* WiT = g_wT + OFF_WIT;
    const float* WhT = g_wT + OFF_WHT;

    // Wh row for this gate, kept in VGPRs for the whole recurrence
    float wh[DM];
    #pragma unroll
    for (int c = 0; c < DM; ++c) wh[c] = WhT[c*GDIM + tid];
    const float tbh = gbh[tid];

    if (tid < DM) H[tid] = 0.f;
    __syncthreads();

    const int gt = tid % 48, tg = tid / 48;      // gx GEMM mapping: 48 g-groups x 8 t-groups
    const int g0 = gt*8, t0 = tg*4;
    const float* c3b = g_c3 + b*SEQ*DM;
    const int lane = tid & 63;
    const int G = tid >> 7, jj = tid & 127;

    for (int tc = 0; tc < 3; ++tc) {
        // ---- gx = c3 @ Wi^T + bi for t in [32tc, 32tc+32), into LDS
        float acc[4][8];
        #pragma unroll
        for (int u = 0; u < 8; ++u) {
            float bv = gbi[g0+u];
            #pragma unroll
            for (int j = 0; j < 4; ++j) acc[j][u] = bv;
        }
        for (int c = 0; c < DM; c += 2) {
            float2 a2[4];
            #pragma unroll
            for (int j = 0; j < 4; ++j)
                a2[j] = *(const float2*)(c3b + (tc*32 + t0 + j)*DM + c);
            const float4 wA0 = *(const float4*)(WiT + c*GDIM + g0);
            const float4 wB0 = *(const float4*)(WiT + c*GDIM + g0 + 4);
            const float4 wA1 = *(const float4*)(WiT + (c+1)*GDIM + g0);
            const float4 wB1 = *(const float4*)(WiT + (c+1)*GDIM + g0 + 4);
            #pragma unroll
            for (int j = 0; j < 4; ++j) {
                fma8(acc, j, a2[j].x, wA0, wB0);
                fma8(acc, j, a2[j].y, wA1, wB1);
            }
        }
        // previous chunk's recurrence ended with a barrier: safe to store
        #pragma unroll
        for (int j = 0; j < 4; ++j)
            #pragma unroll
            for (int u = 0; u < 8; ++u)
                gx[(t0+j)*GXS + g0+u] = acc[j][u];
        __syncthreads();

        // ---- recurrence over 32 time steps
        for (int tl = 0; tl < 32; ++tl) {
            float hv0 = H[lane], hv1 = H[64+lane];   // h lane-spread per wave
            float acc0 = tbh, acc1 = 0.f;
            #pragma unroll
            for (int c = 0; c < 64; ++c) {
                acc0 = fmaf(__int_as_float(__builtin_amdgcn_readlane(__float_as_int(hv0), c)),
                            wh[c], acc0);
                acc1 = fmaf(__int_as_float(__builtin_amdgcn_readlane(__float_as_int(hv1), c)),
                            wh[64+c], acc1);
            }
            float gh = acc0 + acc1;                   // includes bh
            float gxt = gx[tl*GXS + tid];             // includes bi
            if (G == 0)      GS[jj]      = 1.f/(1.f + __expf(-(gxt + gh)));  // r
            else if (G == 1) GS[DM + jj] = 1.f/(1.f + __expf(-(gxt + gh)));  // z
            __syncthreads();
            if (G == 2) {
                float r = GS[jj], z = GS[DM + jj];
                float n = tanhf(gxt + r*gh);
                H[jj] = (1.f - z)*n + z*H[jj];
            }
            __syncthreads();
        }
    }

    // ---- pred = h @ fc_w^T + fc_b -> out[b][i][:]
    if (tid < CIN) {
        float p = fc_b[tid];
        #pragma unroll
        for (int d = 0; d < DM; ++d) p = fmaf(fc_w[tid*DM + d], H[d], p);
        out[(b*PRED + i)*CIN + tid] = p;
    }
}

// ---------------------------------------------------------------- launch
extern "C" void kernel_launch(void* const* d_in, const int* in_sizes, int n_in,
                              void* d_out, int out_size, void* d_ws, size_t ws_size,
                              hipStream_t stream) {
    const float* x_enc  = (const float*)d_in[0];
    // d_in[1] = x_mark (unused by reference)
    const int*   y_mark = (const int*)d_in[2];
    const float* hour_e = (const float*)d_in[3];
    const float* wk_e   = (const float*)d_in[4];
    const float* day_e  = (const float*)d_in[5];
    const float* mon_e  = (const float*)d_in[6];
    const float* W_val  = (const float*)d_in[7];
    const float* b_val  = (const float*)d_in[8];
    const float* c1w    = (const float*)d_in[9];
    const float* c1b    = (const float*)d_in[10];
    const float* c2w    = (const float*)d_in[11];
    const float* c2b    = (const float*)d_in[12];
    const float* c3w    = (const float*)d_in[13];
    const float* c3b    = (const float*)d_in[14];
    const float* Wi     = (const float*)d_in[15];
    const float* Wh     = (const float*)d_in[16];
    const float* gbi    = (const float*)d_in[17];
    const float* gbh    = (const float*)d_in[18];
    const float* fcw    = (const float*)d_in[19];
    const float* fcb    = (const float*)d_in[20];
    float* out = (float*)d_out;

    prep_weights<<<(W_TOTAL + 255)/256, 256, 0, stream>>>(c1w, c2w, c3w, Wi, Wh);

    for (int i = 0; i < PRED; ++i) {
        conv_kernel<<<dim3(B_SZ, 2), 256, 0, stream>>>(i, x_enc, y_mark,
            hour_e, wk_e, day_e, mon_e, W_val, b_val, c1b, c2b, c3b, out);
        gru_kernel<<<B_SZ, GDIM, 0, stream>>>(i, gbi, gbh, fcw, fcb, out);
    }
}

// Round 2
// 37043.292 us; speedup vs baseline: 1.0627x; 1.0627x over previous
//
#include <hip/hip_runtime.h>

#define B_SZ 512
#define SEQ 96
#define PRED 48
#define TOT 144
#define CIN 7
#define DM 128
#define GDIM 384
#define KS 5

#define CSTR 132      // LDS row stride for conv buffer (conflict-safe)

#define W_CONV (KS*DM*DM)            // 81920 per conv layer (layout [k][c][o])
#define OFF_WIT (3*W_CONV)           // WiT [c][384]
#define OFF_WHT (3*W_CONV + DM*GDIM) // WhT [c][384]
#define W_TOTAL (3*W_CONV + 2*DM*GDIM)

// Device-global scratch
__device__ float g_c3[B_SZ*SEQ*DM];      // conv3 output, [b][t][128]
__device__ float g_gx[B_SZ*SEQ*GDIM];    // gate inputs,  [b][t][384]
__device__ float g_wT[W_TOTAL];          // transposed weights

// ---------------------------------------------------------------- prep
__global__ void prep_weights(const float* __restrict__ w1, const float* __restrict__ w2,
                             const float* __restrict__ w3, const float* __restrict__ Wi,
                             const float* __restrict__ Wh) {
    int tid = blockIdx.x*256 + threadIdx.x;
    if (tid < 3*W_CONV) {
        int l = tid / W_CONV, r = tid % W_CONV;
        int o = r & 127, c = (r >> 7) & 127, k = r >> 14;   // r = (k*128+c)*128+o
        const float* w = (l==0) ? w1 : ((l==1) ? w2 : w3);
        g_wT[tid] = w[o*(DM*KS) + c*KS + k];                 // src [o][c][k]
    } else if (tid < W_TOTAL) {
        int r = tid - 3*W_CONV;
        int m = r / (DM*GDIM), q = r % (DM*GDIM);
        int g = q % GDIM, c = q / GDIM;                      // dst [c][g]
        const float* W = (m==0) ? Wi : Wh;
        g_wT[tid] = W[g*DM + c];                             // src [g][c]
    }
}

// 8-wide FMA helper
template<int NJ>
__device__ __forceinline__ void fma8(float (&acc)[NJ][8], int j, float a,
                                     const float4& wA, const float4& wB) {
    acc[j][0] = fmaf(a, wA.x, acc[j][0]);
    acc[j][1] = fmaf(a, wA.y, acc[j][1]);
    acc[j][2] = fmaf(a, wA.z, acc[j][2]);
    acc[j][3] = fmaf(a, wA.w, acc[j][3]);
    acc[j][4] = fmaf(a, wB.x, acc[j][4]);
    acc[j][5] = fmaf(a, wB.y, acc[j][5]);
    acc[j][6] = fmaf(a, wB.z, acc[j][6]);
    acc[j][7] = fmaf(a, wB.w, acc[j][7]);
}

// One in-place LDS conv layer: compute into regs, barrier, write back into buf.
// Output rows q in [0, nrow) (nrow % 4 == 0); out row q = window row winO+q,
// masked to zero outside [0,SEQ). Input rows q..q+4 of buf.
__device__ __forceinline__ void conv_layer_ip(float* __restrict__ buf,
                                              const float* __restrict__ wT,
                                              const float* __restrict__ bias,
                                              int nrow, int winO, int tid) {
    const int og = tid & 15, ttg = tid >> 4;
    const int o0 = og*8, r0 = ttg*4;
    const bool act = (r0 < nrow);
    float acc[4][8];
    if (act) {
        #pragma unroll
        for (int u = 0; u < 8; ++u) {
            float bv = bias[o0+u];
            #pragma unroll
            for (int j = 0; j < 4; ++j) acc[j][u] = bv;
        }
        for (int c = 0; c < DM; c += 2) {
            float2 a2[8];
            #pragma unroll
            for (int m = 0; m < 8; ++m)
                a2[m] = *(const float2*)(buf + (r0+m)*CSTR + c);
            #pragma unroll
            for (int k = 0; k < KS; ++k) {
                const float4 wA0 = *(const float4*)(wT + (k*DM + c)*DM + o0);
                const float4 wB0 = *(const float4*)(wT + (k*DM + c)*DM + o0 + 4);
                const float4 wA1 = *(const float4*)(wT + (k*DM + c+1)*DM + o0);
                const float4 wB1 = *(const float4*)(wT + (k*DM + c+1)*DM + o0 + 4);
                #pragma unroll
                for (int j = 0; j < 4; ++j) {
                    fma8(acc, j, a2[j+k].x, wA0, wB0);
                    fma8(acc, j, a2[j+k].y, wA1, wB1);
                }
            }
        }
    }
    __syncthreads();   // all reads of buf done
    if (act) {
        #pragma unroll
        for (int j = 0; j < 4; ++j) {
            int q = r0 + j, w = winO + q;
            bool valid = (w >= 0) && (w < SEQ);
            #pragma unroll
            for (int u = 0; u < 8; ++u)
                buf[q*CSTR + o0+u] = valid ? fmaxf(acc[j][u], 0.f) : 0.f;
        }
    }
    __syncthreads();   // writes visible for next layer
}

// ------------------------------------------------------------- conv kernel
// grid (512, 2): b = blockIdx.x, chunk cs = 48*blockIdx.y. Computes c3 for
// window rows [cs, cs+48) of step i. Single 60-row LDS buffer (31.7 KB ->
// 4 blocks/CU at 128 VGPRs).
__launch_bounds__(256, 4)
__global__ void conv_kernel(int i, const float* __restrict__ x_enc,
                            const int* __restrict__ y_mark,
                            const float* __restrict__ hour_e, const float* __restrict__ wk_e,
                            const float* __restrict__ day_e, const float* __restrict__ mon_e,
                            const float* __restrict__ W_val, const float* __restrict__ b_val,
                            const float* __restrict__ b1, const float* __restrict__ b2,
                            const float* __restrict__ b3, const float* __restrict__ out) {
    __shared__ float buf[60*CSTR];
    const int tid = threadIdx.x;
    const int b = blockIdx.x;
    const int cs = blockIdx.y * 48;

    // ---- embedding: rows q=0..59 -> window row w = cs-6+q (zero outside [0,96))
    for (int e = tid; e < 60*DM; e += 256) {
        int q = e >> 7, d = e & 127;
        int w = cs - 6 + q;
        float v = 0.f;
        if (w >= 0 && w < SEQ) {
            int p = i + w;
            const float* xr = (p < SEQ) ? (x_enc + (b*SEQ + p)*CIN)
                                        : (out + (b*PRED + (p - SEQ))*CIN);
            v = b_val[d];
            #pragma unroll
            for (int c = 0; c < CIN; ++c) v = fmaf(xr[c], W_val[d*CIN + c], v);
            const int* ym = y_mark + (b*TOT + p)*4;
            v += hour_e[ym[0]*DM + d] + wk_e[ym[1]*DM + d]
               + day_e[ym[2]*DM + d] + mon_e[ym[3]*DM + d];
        }
        buf[q*CSTR + d] = v;
    }
    __syncthreads();
    conv_layer_ip(buf, g_wT,          b1, 56, cs - 4, tid);  // c1 -> rows 0..55
    conv_layer_ip(buf, g_wT + W_CONV, b2, 52, cs - 2, tid);  // c2 -> rows 0..51
    // ---- c3 -> global (48 rows, all valid). 16 ttg x 3 rows: all 256 threads.
    {
        const int og = tid & 15, ttg = tid >> 4;
        const int o0 = og*8, r0 = ttg*3;
        const float* wT = g_wT + 2*W_CONV;
        float acc[3][8];
        #pragma unroll
        for (int u = 0; u < 8; ++u) {
            float bv = b3[o0+u];
            #pragma unroll
            for (int j = 0; j < 3; ++j) acc[j][u] = bv;
        }
        for (int c = 0; c < DM; c += 2) {
            float2 a2[7];
            #pragma unroll
            for (int m = 0; m < 7; ++m)
                a2[m] = *(const float2*)(buf + (r0+m)*CSTR + c);
            #pragma unroll
            for (int k = 0; k < KS; ++k) {
                const float4 wA0 = *(const float4*)(wT + (k*DM + c)*DM + o0);
                const float4 wB0 = *(const float4*)(wT + (k*DM + c)*DM + o0 + 4);
                const float4 wA1 = *(const float4*)(wT + (k*DM + c+1)*DM + o0);
                const float4 wB1 = *(const float4*)(wT + (k*DM + c+1)*DM + o0 + 4);
                #pragma unroll
                for (int j = 0; j < 3; ++j) {
                    fma8(acc, j, a2[j+k].x, wA0, wB0);
                    fma8(acc, j, a2[j+k].y, wA1, wB1);
                }
            }
        }
        #pragma unroll
        for (int j = 0; j < 3; ++j) {
            int t = cs + r0 + j;
            #pragma unroll
            for (int u = 0; u < 8; ++u)
                g_c3[(b*SEQ + t)*DM + o0+u] = fmaxf(acc[j][u], 0.f);
        }
    }
}

// -------------------------------------------------------------- gx GEMM
// grid (512, 3): block computes gx (= c3 @ Wi^T + bi) for t in [32*tc, +32).
__launch_bounds__(384, 4)
__global__ void gx_gemm(const float* __restrict__ gbi) {
    __shared__ float At[32*DM];
    const int tid = threadIdx.x;
    const int b = blockIdx.x, tc = blockIdx.y;
    const float* c3b = g_c3 + ((size_t)b*SEQ + tc*32)*DM;
    for (int idx = tid; idx < 32*DM/4; idx += 384)
        ((float4*)At)[idx] = ((const float4*)c3b)[idx];
    __syncthreads();

    const int gt = tid % 48, tg = tid / 48;
    const int g0 = gt*8, t0 = tg*4;
    const float* WiT = g_wT + OFF_WIT;
    float acc[4][8];
    #pragma unroll
    for (int u = 0; u < 8; ++u) {
        float bv = gbi[g0+u];
        #pragma unroll
        for (int j = 0; j < 4; ++j) acc[j][u] = bv;
    }
    for (int c = 0; c < DM; c += 2) {
        float2 a2[4];
        #pragma unroll
        for (int j = 0; j < 4; ++j)
            a2[j] = *(const float2*)(At + (t0+j)*DM + c);
        const float4 wA0 = *(const float4*)(WiT + c*GDIM + g0);
        const float4 wB0 = *(const float4*)(WiT + c*GDIM + g0 + 4);
        const float4 wA1 = *(const float4*)(WiT + (c+1)*GDIM + g0);
        const float4 wB1 = *(const float4*)(WiT + (c+1)*GDIM + g0 + 4);
        #pragma unroll
        for (int j = 0; j < 4; ++j) {
            fma8(acc, j, a2[j].x, wA0, wB0);
            fma8(acc, j, a2[j].y, wA1, wB1);
        }
    }
    float* gxo = g_gx + ((size_t)b*SEQ + tc*32)*GDIM;
    #pragma unroll
    for (int j = 0; j < 4; ++j) {
        #pragma unroll
        for (int u = 0; u < 8; u += 4)
            *(float4*)(gxo + (t0+j)*GDIM + g0+u) = *(float4*)&acc[j][u];
    }
}

// -------------------------------------------------------------- recurrence
// grid 512 (one batch row per block), 384 threads (thread = gate g).
// Wh row resident in VGPRs; launch_bounds(384,3) caps at ~170 regs (no spill).
__launch_bounds__(GDIM, 3)
__global__ void gru_rec(int i, const float* __restrict__ gbh,
                        const float* __restrict__ fc_w, const float* __restrict__ fc_b,
                        float* __restrict__ out) {
    __shared__ float H[DM];
    __shared__ float GS[2*DM];
    const int tid = threadIdx.x;
    const int b = blockIdx.x;
    const float* WhT = g_wT + OFF_WHT;

    float wh[DM];
    #pragma unroll
    for (int c = 0; c < DM; ++c) wh[c] = WhT[c*GDIM + tid];
    const float tbh = gbh[tid];

    if (tid < DM) H[tid] = 0.f;
    __syncthreads();

    const int lane = tid & 63;
    const int G = tid >> 7, jj = tid & 127;
    const float* gxb = g_gx + (size_t)b*SEQ*GDIM;

    for (int t = 0; t < SEQ; ++t) {
        float hv0 = H[lane], hv1 = H[64+lane];
        float acc0 = tbh, acc1 = 0.f;
        #pragma unroll
        for (int c = 0; c < 64; ++c) {
            acc0 = fmaf(__int_as_float(__builtin_amdgcn_readlane(__float_as_int(hv0), c)),
                        wh[c], acc0);
            acc1 = fmaf(__int_as_float(__builtin_amdgcn_readlane(__float_as_int(hv1), c)),
                        wh[64+c], acc1);
        }
        float gh = acc0 + acc1;                   // includes bh
        float gxt = gxb[t*GDIM + tid];            // includes bi
        if (G == 0)      GS[jj]      = 1.f/(1.f + __expf(-(gxt + gh)));  // r
        else if (G == 1) GS[DM + jj] = 1.f/(1.f + __expf(-(gxt + gh)));  // z
        __syncthreads();
        if (G == 2) {
            float r = GS[jj], z = GS[DM + jj];
            float n = tanhf(gxt + r*gh);
            H[jj] = (1.f - z)*n + z*H[jj];
        }
        __syncthreads();
    }

    if (tid < CIN) {
        float p = fc_b[tid];
        #pragma unroll
        for (int d = 0; d < DM; ++d) p = fmaf(fc_w[tid*DM + d], H[d], p);
        out[(b*PRED + i)*CIN + tid] = p;
    }
}

// ---------------------------------------------------------------- launch
extern "C" void kernel_launch(void* const* d_in, const int* in_sizes, int n_in,
                              void* d_out, int out_size, void* d_ws, size_t ws_size,
                              hipStream_t stream) {
    const float* x_enc  = (const float*)d_in[0];
    const int*   y_mark = (const int*)d_in[2];
    const float* hour_e = (const float*)d_in[3];
    const float* wk_e   = (const float*)d_in[4];
    const float* day_e  = (const float*)d_in[5];
    const float* mon_e  = (const float*)d_in[6];
    const float* W_val  = (const float*)d_in[7];
    const float* b_val  = (const float*)d_in[8];
    const float* c1w    = (const float*)d_in[9];
    const float* c1b    = (const float*)d_in[10];
    const float* c2w    = (const float*)d_in[11];
    const float* c2b    = (const float*)d_in[12];
    const float* c3w    = (const float*)d_in[13];
    const float* c3b    = (const float*)d_in[14];
    const float* Wi     = (const float*)d_in[15];
    const float* Wh     = (const float*)d_in[16];
    const float* gbi    = (const float*)d_in[17];
    const float* gbh    = (const float*)d_in[18];
    const float* fcw    = (const float*)d_in[19];
    const float* fcb    = (const float*)d_in[20];
    float* out = (float*)d_out;

    prep_weights<<<(W_TOTAL + 255)/256, 256, 0, stream>>>(c1w, c2w, c3w, Wi, Wh);

    for (int i = 0; i < PRED; ++i) {
        conv_kernel<<<dim3(B_SZ, 2), 256, 0, stream>>>(i, x_enc, y_mark,
            hour_e, wk_e, day_e, mon_e, W_val, b_val, c1b, c2b, c3b, out);
        gx_gemm<<<dim3(B_SZ, 3), GDIM, 0, stream>>>(gbi);
        gru_rec<<<B_SZ, GDIM, 0, stream>>>(i, gbh, fcw, fcb, out);
    }
}

// Round 3
// 32229.330 us; speedup vs baseline: 1.2214x; 1.1494x over previous
//
#include <hip/hip_runtime.h>

#define B_SZ 512
#define SEQ 96
#define PRED 48
#define TOT 144
#define CIN 7
#define DM 128
#define GDIM 384
#define KS 5

#define CSTR 132      // LDS row stride for conv buffer (conflict-safe)

#define W_CONV (KS*DM*DM)            // 81920 per conv layer (layout [k][c][o])
#define OFF_WIT (3*W_CONV)           // WiT [c][384]
#define OFF_WHT (3*W_CONV + DM*GDIM) // WhT [c][384]
#define W_TOTAL (3*W_CONV + 2*DM*GDIM)

// Device-global scratch
__device__ float g_gx[B_SZ*SEQ*GDIM];    // gate inputs,  [b][t][384]
__device__ float g_wT[W_TOTAL];          // transposed weights

// ---------------------------------------------------------------- prep
__global__ void prep_weights(const float* __restrict__ w1, const float* __restrict__ w2,
                             const float* __restrict__ w3, const float* __restrict__ Wi,
                             const float* __restrict__ Wh) {
    int tid = blockIdx.x*256 + threadIdx.x;
    if (tid < 3*W_CONV) {
        int l = tid / W_CONV, r = tid % W_CONV;
        int o = r & 127, c = (r >> 7) & 127, k = r >> 14;   // r = (k*128+c)*128+o
        const float* w = (l==0) ? w1 : ((l==1) ? w2 : w3);
        g_wT[tid] = w[o*(DM*KS) + c*KS + k];                 // src [o][c][k]
    } else if (tid < W_TOTAL) {
        int r = tid - 3*W_CONV;
        int m = r / (DM*GDIM), q = r % (DM*GDIM);
        int g = q % GDIM, c = q / GDIM;                      // dst [c][g]
        const float* W = (m==0) ? Wi : Wh;
        g_wT[tid] = W[g*DM + c];                             // src [g][c]
    }
}

// 8-wide FMA helper
template<int NJ>
__device__ __forceinline__ void fma8(float (&acc)[NJ][8], int j, float a,
                                     const float4& wA, const float4& wB) {
    acc[j][0] = fmaf(a, wA.x, acc[j][0]);
    acc[j][1] = fmaf(a, wA.y, acc[j][1]);
    acc[j][2] = fmaf(a, wA.z, acc[j][2]);
    acc[j][3] = fmaf(a, wA.w, acc[j][3]);
    acc[j][4] = fmaf(a, wB.x, acc[j][4]);
    acc[j][5] = fmaf(a, wB.y, acc[j][5]);
    acc[j][6] = fmaf(a, wB.z, acc[j][6]);
    acc[j][7] = fmaf(a, wB.w, acc[j][7]);
}

// Chunked in-place conv layer: weights staged 8 channels at a time into wbuf
// (shared by whole block -> L2 traffic 1x per block instead of 1x per wave).
// Out rows q in [0,nrow), out row q = window row winO+q, zero outside [0,SEQ).
template<int NJ>
__device__ __forceinline__ void conv_layer_chunked(float* __restrict__ buf,
                                                   float* __restrict__ wbuf,
                                                   const float* __restrict__ wT,
                                                   const float* __restrict__ bias,
                                                   int nrow, int winO, int tid) {
    const int og = tid & 15, ttg = tid >> 4;
    const int o0 = og*8, r0 = ttg*NJ;
    const bool act = (r0 < nrow);
    float acc[NJ][8];
    #pragma unroll
    for (int u = 0; u < 8; ++u) {
        float bv = bias[o0+u];
        #pragma unroll
        for (int j = 0; j < NJ; ++j) acc[j][u] = bv;
    }
    for (int cc = 0; cc < DM/8; ++cc) {
        __syncthreads();            // prior chunk's FMA reads of wbuf done
        #pragma unroll
        for (int k = 0; k < KS; ++k)   // stage 8 channels: 5 x 1024 floats, contiguous per k
            ((float4*)wbuf)[k*256 + tid] = ((const float4*)(wT + (k*DM + cc*8)*DM))[tid];
        __syncthreads();
        if (act) {
            const int c0 = cc*8;
            #pragma unroll
            for (int cj = 0; cj < 8; cj += 2) {
                float2 a2[NJ+4];
                #pragma unroll
                for (int m = 0; m < NJ+4; ++m)
                    a2[m] = *(const float2*)(buf + (r0+m)*CSTR + c0 + cj);
                #pragma unroll
                for (int k = 0; k < KS; ++k) {
                    const float4 wA0 = *(const float4*)(wbuf + (k*8+cj)*DM + o0);
                    const float4 wB0 = *(const float4*)(wbuf + (k*8+cj)*DM + o0 + 4);
                    const float4 wA1 = *(const float4*)(wbuf + (k*8+cj+1)*DM + o0);
                    const float4 wB1 = *(const float4*)(wbuf + (k*8+cj+1)*DM + o0 + 4);
                    #pragma unroll
                    for (int j = 0; j < NJ; ++j) {
                        fma8(acc, j, a2[j+k].x, wA0, wB0);
                        fma8(acc, j, a2[j+k].y, wA1, wB1);
                    }
                }
            }
        }
    }
    __syncthreads();   // all reads of buf done
    if (act) {
        #pragma unroll
        for (int j = 0; j < NJ; ++j) {
            int q = r0 + j, w = winO + q;
            bool valid = (w >= 0) && (w < SEQ);
            #pragma unroll
            for (int u = 0; u < 8; ++u)
                buf[q*CSTR + o0+u] = valid ? fmaxf(acc[j][u], 0.f) : 0.f;
        }
    }
    __syncthreads();
}

// ------------------------------------------------------------- fused conv+gx
// grid (512, 2): b = blockIdx.x, chunk cs = 48*blockIdx.y. Computes c3 for
// window rows [cs, cs+48) of step i in LDS, then gx = c3 @ WiT + bi -> g_gx.
__launch_bounds__(256, 3)
__global__ void conv_gx_kernel(int i, const float* __restrict__ x_enc,
                            const int* __restrict__ y_mark,
                            const float* __restrict__ hour_e, const float* __restrict__ wk_e,
                            const float* __restrict__ day_e, const float* __restrict__ mon_e,
                            const float* __restrict__ W_val, const float* __restrict__ b_val,
                            const float* __restrict__ b1, const float* __restrict__ b2,
                            const float* __restrict__ b3, const float* __restrict__ gbi,
                            const float* __restrict__ out) {
    __shared__ float buf[60*CSTR];        // 31,680 B activations
    __shared__ float wbuf[KS*8*DM];       // 20,480 B staged weight chunk
    const int tid = threadIdx.x;
    const int b = blockIdx.x;
    const int cs = blockIdx.y * 48;

    // ---- embedding: rows q=0..59 -> window row w = cs-6+q (zero outside [0,96))
    for (int e = tid; e < 60*DM; e += 256) {
        int q = e >> 7, d = e & 127;
        int w = cs - 6 + q;
        float v = 0.f;
        if (w >= 0 && w < SEQ) {
            int p = i + w;
            const float* xr = (p < SEQ) ? (x_enc + (b*SEQ + p)*CIN)
                                        : (out + (b*PRED + (p - SEQ))*CIN);
            v = b_val[d];
            #pragma unroll
            for (int c = 0; c < CIN; ++c) v = fmaf(xr[c], W_val[d*CIN + c], v);
            const int* ym = y_mark + (b*TOT + p)*4;
            v += hour_e[ym[0]*DM + d] + wk_e[ym[1]*DM + d]
               + day_e[ym[2]*DM + d] + mon_e[ym[3]*DM + d];
        }
        buf[q*CSTR + d] = v;
    }
    // (conv_layer_chunked starts with __syncthreads)
    conv_layer_chunked<4>(buf, wbuf, g_wT,          b1, 56, cs - 4, tid);  // c1: rows 0..55
    conv_layer_chunked<4>(buf, wbuf, g_wT + W_CONV, b2, 52, cs - 2, tid);  // c2: rows 0..51
    conv_layer_chunked<3>(buf, wbuf, g_wT + 2*W_CONV, b3, 48, cs,   tid);  // c3: rows 0..47 (always valid)

    // ---- gx = c3 @ WiT + bi for the 48 rows; thread tile: 3 rows x 24 g
    const int og = tid & 15, ttg = tid >> 4;
    const int g0 = og*24, r0 = ttg*3;
    const float* WiT = g_wT + OFF_WIT;
    float ga[3][24];
    #pragma unroll
    for (int e = 0; e < 24; ++e) {
        float bv = gbi[g0+e];
        #pragma unroll
        for (int j = 0; j < 3; ++j) ga[j][e] = bv;
    }
    for (int cc = 0; cc < DM/8; ++cc) {
        __syncthreads();
        #pragma unroll
        for (int s = 0; s < 3; ++s)   // stage WiT rows cc*8..+7 (3072 floats)
            ((float4*)wbuf)[s*256 + tid] = ((const float4*)(WiT + cc*8*GDIM))[s*256 + tid];
        __syncthreads();
        const int c0 = cc*8;
        #pragma unroll
        for (int cj = 0; cj < 8; cj += 2) {
            float2 a2[3];
            #pragma unroll
            for (int m = 0; m < 3; ++m)
                a2[m] = *(const float2*)(buf + (r0+m)*CSTR + c0 + cj);
            float4 w4[6];
            #pragma unroll
            for (int q = 0; q < 6; ++q)
                w4[q] = *(const float4*)(wbuf + cj*GDIM + g0 + q*4);
            const float* wv = (const float*)w4;
            #pragma unroll
            for (int j = 0; j < 3; ++j)
                #pragma unroll
                for (int e = 0; e < 24; ++e)
                    ga[j][e] = fmaf(a2[j].x, wv[e], ga[j][e]);
            #pragma unroll
            for (int q = 0; q < 6; ++q)
                w4[q] = *(const float4*)(wbuf + (cj+1)*GDIM + g0 + q*4);
            #pragma unroll
            for (int j = 0; j < 3; ++j)
                #pragma unroll
                for (int e = 0; e < 24; ++e)
                    ga[j][e] = fmaf(a2[j].y, wv[e], ga[j][e]);
        }
    }
    float* gxo = g_gx + ((size_t)b*SEQ + cs)*GDIM;
    #pragma unroll
    for (int j = 0; j < 3; ++j)
        #pragma unroll
        for (int q = 0; q < 6; ++q)
            *(float4*)(gxo + (r0+j)*GDIM + g0 + q*4) = *(const float4*)&ga[j][q*4];
}

// -------------------------------------------------------------- recurrence
// grid 512 (one batch row per block), 384 threads (thread = gate g).
// Wh row resident in VGPRs; launch_bounds(384,3) caps at ~170 regs (no spill).
__launch_bounds__(GDIM, 3)
__global__ void gru_rec(int i, const float* __restrict__ gbh,
                        const float* __restrict__ fc_w, const float* __restrict__ fc_b,
                        float* __restrict__ out) {
    __shared__ float H[DM];
    __shared__ float GS[2*DM];
    const int tid = threadIdx.x;
    const int b = blockIdx.x;
    const float* WhT = g_wT + OFF_WHT;

    float wh[DM];
    #pragma unroll
    for (int c = 0; c < DM; ++c) wh[c] = WhT[c*GDIM + tid];
    const float tbh = gbh[tid];

    if (tid < DM) H[tid] = 0.f;
    __syncthreads();

    const int lane = tid & 63;
    const int G = tid >> 7, jj = tid & 127;
    const float* gxb = g_gx + (size_t)b*SEQ*GDIM;

    for (int t = 0; t < SEQ; ++t) {
        float hv0 = H[lane], hv1 = H[64+lane];
        float acc0 = tbh, acc1 = 0.f;
        #pragma unroll
        for (int c = 0; c < 64; ++c) {
            acc0 = fmaf(__int_as_float(__builtin_amdgcn_readlane(__float_as_int(hv0), c)),
                        wh[c], acc0);
            acc1 = fmaf(__int_as_float(__builtin_amdgcn_readlane(__float_as_int(hv1), c)),
                        wh[64+c], acc1);
        }
        float gh = acc0 + acc1;                   // includes bh
        float gxt = gxb[t*GDIM + tid];            // includes bi
        if (G == 0)      GS[jj]      = 1.f/(1.f + __expf(-(gxt + gh)));  // r
        else if (G == 1) GS[DM + jj] = 1.f/(1.f + __expf(-(gxt + gh)));  // z
        __syncthreads();
        if (G == 2) {
            float r = GS[jj], z = GS[DM + jj];
            float n = tanhf(gxt + r*gh);
            H[jj] = (1.f - z)*n + z*H[jj];
        }
        __syncthreads();
    }

    if (tid < CIN) {
        float p = fc_b[tid];
        #pragma unroll
        for (int d = 0; d < DM; ++d) p = fmaf(fc_w[tid*DM + d], H[d], p);
        out[(b*PRED + i)*CIN + tid] = p;
    }
}

// ---------------------------------------------------------------- launch
extern "C" void kernel_launch(void* const* d_in, const int* in_sizes, int n_in,
                              void* d_out, int out_size, void* d_ws, size_t ws_size,
                              hipStream_t stream) {
    const float* x_enc  = (const float*)d_in[0];
    const int*   y_mark = (const int*)d_in[2];
    const float* hour_e = (const float*)d_in[3];
    const float* wk_e   = (const float*)d_in[4];
    const float* day_e  = (const float*)d_in[5];
    const float* mon_e  = (const float*)d_in[6];
    const float* W_val  = (const float*)d_in[7];
    const float* b_val  = (const float*)d_in[8];
    const float* c1w    = (const float*)d_in[9];
    const float* c1b    = (const float*)d_in[10];
    const float* c2w    = (const float*)d_in[11];
    const float* c2b    = (const float*)d_in[12];
    const float* c3w    = (const float*)d_in[13];
    const float* c3b    = (const float*)d_in[14];
    const float* Wi     = (const float*)d_in[15];
    const float* Wh     = (const float*)d_in[16];
    const float* gbi    = (const float*)d_in[17];
    const float* gbh    = (const float*)d_in[18];
    const float* fcw    = (const float*)d_in[19];
    const float* fcb    = (const float*)d_in[20];
    float* out = (float*)d_out;

    prep_weights<<<(W_TOTAL + 255)/256, 256, 0, stream>>>(c1w, c2w, c3w, Wi, Wh);

    for (int i = 0; i < PRED; ++i) {
        conv_gx_kernel<<<dim3(B_SZ, 2), 256, 0, stream>>>(i, x_enc, y_mark,
            hour_e, wk_e, day_e, mon_e, W_val, b_val, c1b, c2b, c3b, gbi, out);
        gru_rec<<<B_SZ, GDIM, 0, stream>>>(i, gbh, fcw, fcb, out);
    }
}

// Round 4
// 19869.241 us; speedup vs baseline: 1.9813x; 1.6221x over previous
//
#include <hip/hip_runtime.h>

#define B_SZ 512
#define SEQ 96
#define PRED 48
#define TOT 144
#define CIN 7
#define DM 128
#define GDIM 384
#define KS 5

#define CSTR 132              // LDS row stride for activation buffers
#define WROW 136              // swizzled LDS weight row (128 + pad)
#define SWZ(o) ((o) + ((((o) >> 6)) << 2))   // bank swizzle: pad 4 every 64 floats

#define W_CONV (KS*DM*DM)            // 81920 per conv layer (layout [k][c][o])
#define OFF_WIT (3*W_CONV)           // WiT [c][384]
#define OFF_WHT (3*W_CONV + DM*GDIM) // WhT [c][384]
#define W_TOTAL (3*W_CONV + 2*DM*GDIM)

// Device-global scratch
__device__ float g_gxg[(size_t)B_SZ*TOT*GDIM];  // invariant gx cache, [b][p][384]
__device__ float g_gxe[B_SZ*12*GDIM];           // per-step edge gx, [b][12][384]
__device__ float g_wT[W_TOTAL];                 // transposed weights

// ---------------------------------------------------------------- prep
__global__ void prep_weights(const float* __restrict__ w1, const float* __restrict__ w2,
                             const float* __restrict__ w3, const float* __restrict__ Wi,
                             const float* __restrict__ Wh) {
    int tid = blockIdx.x*256 + threadIdx.x;
    if (tid < 3*W_CONV) {
        int l = tid / W_CONV, r = tid % W_CONV;
        int o = r & 127, c = (r >> 7) & 127, k = r >> 14;   // r = (k*128+c)*128+o
        const float* w = (l==0) ? w1 : ((l==1) ? w2 : w3);
        g_wT[tid] = w[o*(DM*KS) + c*KS + k];                 // src [o][c][k]
    } else if (tid < W_TOTAL) {
        int r = tid - 3*W_CONV;
        int m = r / (DM*GDIM), q = r % (DM*GDIM);
        int g = q % GDIM, c = q / GDIM;                      // dst [c][g]
        const float* W = (m==0) ? Wi : Wh;
        g_wT[tid] = W[g*DM + c];                             // src [g][c]
    }
}

// ---------------------------------------------------------------- fma helpers
template<int NJ>
__device__ __forceinline__ void fma8(float (&acc)[NJ][8], int j, float a,
                                     const float4& wA, const float4& wB) {
    acc[j][0] = fmaf(a, wA.x, acc[j][0]);
    acc[j][1] = fmaf(a, wA.y, acc[j][1]);
    acc[j][2] = fmaf(a, wA.z, acc[j][2]);
    acc[j][3] = fmaf(a, wA.w, acc[j][3]);
    acc[j][4] = fmaf(a, wB.x, acc[j][4]);
    acc[j][5] = fmaf(a, wB.y, acc[j][5]);
    acc[j][6] = fmaf(a, wB.z, acc[j][6]);
    acc[j][7] = fmaf(a, wB.w, acc[j][7]);
}

__device__ __forceinline__ void fma8v(float (&acc)[8], float a,
                                      const float4& wA, const float4& wB) {
    acc[0] = fmaf(a, wA.x, acc[0]);
    acc[1] = fmaf(a, wA.y, acc[1]);
    acc[2] = fmaf(a, wA.z, acc[2]);
    acc[3] = fmaf(a, wA.w, acc[3]);
    acc[4] = fmaf(a, wB.x, acc[4]);
    acc[5] = fmaf(a, wB.y, acc[5]);
    acc[6] = fmaf(a, wB.z, acc[6]);
    acc[7] = fmaf(a, wB.w, acc[7]);
}

// stage 8 channels of conv weights (swizzled) into wbuf: rows [k*8+cj] x 128 outs
__device__ __forceinline__ void stage_conv_chunk(float* __restrict__ wbuf,
                                                 const float* __restrict__ wT,
                                                 int cc, int tid) {
    const int cj = tid >> 5, oo = (tid & 31) * 4;
    #pragma unroll
    for (int k = 0; k < KS; ++k)
        *(float4*)(wbuf + (k*8 + cj)*WROW + SWZ(oo)) =
            *(const float4*)(wT + (k*DM + cc*8 + cj)*DM + oo);
}

// Chunked in-place conv layer (init kernel): weights staged in swizzled wbuf.
// Out rows q in [0,nrow), out row q = window row winO+q, zero outside [0,SEQ).
template<int NJ>
__device__ __forceinline__ void conv_layer_chunked(float* __restrict__ buf,
                                                   float* __restrict__ wbuf,
                                                   const float* __restrict__ wT,
                                                   const float* __restrict__ bias,
                                                   int nrow, int winO, int tid) {
    const int og = tid & 15, ttg = tid >> 4;
    const int o0 = og*8, so0 = SWZ(o0), r0 = ttg*NJ;
    const bool act = (r0 < nrow);
    float acc[NJ][8];
    #pragma unroll
    for (int u = 0; u < 8; ++u) {
        float bv = bias[o0+u];
        #pragma unroll
        for (int j = 0; j < NJ; ++j) acc[j][u] = bv;
    }
    for (int cc = 0; cc < DM/8; ++cc) {
        __syncthreads();            // prior chunk's FMA reads of wbuf done
        stage_conv_chunk(wbuf, wT, cc, tid);
        __syncthreads();
        if (act) {
            const int c0 = cc*8;
            #pragma unroll
            for (int cj = 0; cj < 8; cj += 2) {
                float2 a2[NJ+4];
                #pragma unroll
                for (int m = 0; m < NJ+4; ++m)
                    a2[m] = *(const float2*)(buf + (r0+m)*CSTR + c0 + cj);
                #pragma unroll
                for (int k = 0; k < KS; ++k) {
                    const float4 wA0 = *(const float4*)(wbuf + (k*8+cj)*WROW + so0);
                    const float4 wB0 = *(const float4*)(wbuf + (k*8+cj)*WROW + so0 + 4);
                    const float4 wA1 = *(const float4*)(wbuf + (k*8+cj+1)*WROW + so0);
                    const float4 wB1 = *(const float4*)(wbuf + (k*8+cj+1)*WROW + so0 + 4);
                    #pragma unroll
                    for (int j = 0; j < NJ; ++j) {
                        fma8(acc, j, a2[j+k].x, wA0, wB0);
                        fma8(acc, j, a2[j+k].y, wA1, wB1);
                    }
                }
            }
        }
    }
    __syncthreads();   // all reads of buf done
    if (act) {
        #pragma unroll
        for (int j = 0; j < NJ; ++j) {
            int q = r0 + j, w = winO + q;
            bool valid = (w >= 0) && (w < SEQ);
            #pragma unroll
            for (int u = 0; u < 8; ++u)
                buf[q*CSTR + o0+u] = valid ? fmaxf(acc[j][u], 0.f) : 0.f;
        }
    }
    __syncthreads();
}

// ------------------------------------------------------------- init kernel
// Step 0's full conv cascade; stores invariant gx rows w in [6,90) to g_gxg[b][w].
// grid (512, 2): b = blockIdx.x, chunk cs = 48*blockIdx.y.
__launch_bounds__(256, 3)
__global__ void init_kernel(const float* __restrict__ x_enc,
                            const int* __restrict__ y_mark,
                            const float* __restrict__ hour_e, const float* __restrict__ wk_e,
                            const float* __restrict__ day_e, const float* __restrict__ mon_e,
                            const float* __restrict__ W_val, const float* __restrict__ b_val,
                            const float* __restrict__ b1, const float* __restrict__ b2,
                            const float* __restrict__ b3, const float* __restrict__ gbi) {
    __shared__ float buf[60*CSTR];        // 31,680 B activations
    __shared__ float wbuf[KS*8*WROW];     // 21,760 B staged weight chunk
    const int tid = threadIdx.x;
    const int b = blockIdx.x;
    const int cs = blockIdx.y * 48;

    // ---- embedding: rows q=0..59 -> window row w = cs-6+q (zero outside [0,96))
    // i == 0 here: position p == w, all from x_enc.
    for (int e = tid; e < 60*DM; e += 256) {
        int q = e >> 7, d = e & 127;
        int w = cs - 6 + q;
        float v = 0.f;
        if (w >= 0 && w < SEQ) {
            const float* xr = x_enc + (b*SEQ + w)*CIN;
            v = b_val[d];
            #pragma unroll
            for (int c = 0; c < CIN; ++c) v = fmaf(xr[c], W_val[d*CIN + c], v);
            const int* ym = y_mark + (b*TOT + w)*4;
            v += hour_e[ym[0]*DM + d] + wk_e[ym[1]*DM + d]
               + day_e[ym[2]*DM + d] + mon_e[ym[3]*DM + d];
        }
        buf[q*CSTR + d] = v;
    }
    conv_layer_chunked<4>(buf, wbuf, g_wT,            b1, 56, cs - 4, tid);
    conv_layer_chunked<4>(buf, wbuf, g_wT + W_CONV,   b2, 52, cs - 2, tid);
    conv_layer_chunked<3>(buf, wbuf, g_wT + 2*W_CONV, b3, 48, cs,     tid);

    // ---- gx = c3 @ WiT + bi; store rows w in [6,90) to g_gxg[b][w]
    const int og = tid & 15, ttg = tid >> 4;
    const int g0 = og*24, r0 = ttg*3;
    const float* WiT = g_wT + OFF_WIT;
    float ga[3][24];
    #pragma unroll
    for (int e = 0; e < 24; ++e) {
        float bv = gbi[g0+e];
        #pragma unroll
        for (int j = 0; j < 3; ++j) ga[j][e] = bv;
    }
    for (int cc = 0; cc < DM/8; ++cc) {
        __syncthreads();
        #pragma unroll
        for (int s = 0; s < 3; ++s)   // stage WiT rows cc*8..+7 (3072 floats)
            ((float4*)wbuf)[s*256 + tid] = ((const float4*)(WiT + cc*8*GDIM))[s*256 + tid];
        __syncthreads();
        const int c0 = cc*8;
        #pragma unroll
        for (int cj = 0; cj < 8; cj += 2) {
            float2 a2[3];
            #pragma unroll
            for (int m = 0; m < 3; ++m)
                a2[m] = *(const float2*)(buf + (r0+m)*CSTR + c0 + cj);
            float4 w4[6];
            #pragma unroll
            for (int q = 0; q < 6; ++q)
                w4[q] = *(const float4*)(wbuf + cj*GDIM + g0 + q*4);
            const float* wv = (const float*)w4;
            #pragma unroll
            for (int j = 0; j < 3; ++j)
                #pragma unroll
                for (int e = 0; e < 24; ++e)
                    ga[j][e] = fmaf(a2[j].x, wv[e], ga[j][e]);
            #pragma unroll
            for (int q = 0; q < 6; ++q)
                w4[q] = *(const float4*)(wbuf + (cj+1)*GDIM + g0 + q*4);
            #pragma unroll
            for (int j = 0; j < 3; ++j)
                #pragma unroll
                for (int e = 0; e < 24; ++e)
                    ga[j][e] = fmaf(a2[j].y, wv[e], ga[j][e]);
        }
    }
    #pragma unroll
    for (int j = 0; j < 3; ++j) {
        int w = cs + r0 + j;
        if (w >= 6 && w < 90) {
            float* gxo = g_gxg + ((size_t)b*TOT + w)*GDIM + g0;
            #pragma unroll
            for (int q = 0; q < 6; ++q)
                *(float4*)(gxo + q*4) = *(const float4*)&ga[j][q*4];
        }
    }
}

// ------------------------------------------------------------- step layer
// In-place conv layer over a 20-row buffer. Out rows q in [0,nrow) (<=16),
// out row q = window row wbase+q, zero outside [0,SEQ). One row per ttg.
__device__ __forceinline__ void step_layer(float* __restrict__ buf,
                                           float* __restrict__ wbuf,
                                           const float* __restrict__ wT,
                                           const float* __restrict__ bias,
                                           int nrow, int wbase, int tid) {
    const int og = tid & 15, ttg = tid >> 4;
    const int o0 = og*8, so0 = SWZ(o0);
    const bool act = (ttg < nrow);
    float acc[8];
    #pragma unroll
    for (int u = 0; u < 8; ++u) acc[u] = bias[o0+u];
    for (int cc = 0; cc < DM/8; ++cc) {
        __syncthreads();
        stage_conv_chunk(wbuf, wT, cc, tid);
        __syncthreads();
        if (act) {
            const int c0 = cc*8;
            #pragma unroll
            for (int cj = 0; cj < 8; cj += 2) {
                float2 a2[5];
                #pragma unroll
                for (int m = 0; m < 5; ++m)
                    a2[m] = *(const float2*)(buf + (ttg+m)*CSTR + c0 + cj);
                #pragma unroll
                for (int k = 0; k < KS; ++k) {
                    const float4 wA0 = *(const float4*)(wbuf + (k*8+cj)*WROW + so0);
                    const float4 wB0 = *(const float4*)(wbuf + (k*8+cj)*WROW + so0 + 4);
                    const float4 wA1 = *(const float4*)(wbuf + (k*8+cj+1)*WROW + so0);
                    const float4 wB1 = *(const float4*)(wbuf + (k*8+cj+1)*WROW + so0 + 4);
                    fma8v(acc, a2[k].x, wA0, wB0);
                    fma8v(acc, a2[k].y, wA1, wB1);
                }
            }
        }
    }
    __syncthreads();   // all reads of buf done
    if (act) {
        int w = wbase + ttg;
        bool valid = (w >= 0) && (w < SEQ);
        #pragma unroll
        for (int u = 0; u < 8; ++u)
            buf[ttg*CSTR + o0+u] = valid ? fmaxf(acc[u], 0.f) : 0.f;
    }
    __syncthreads();
}

// ------------------------------------------------------------- step kernel
// grid (512, 2): gy=0 -> left edge (c3 rows w in [0,8)), gy=1 -> right edge +
// new invariant position (c3 rows w in [89,97)). 20-row cascade per block.
__launch_bounds__(256, 4)
__global__ void step_kernel(int i, const float* __restrict__ x_enc,
                            const int* __restrict__ y_mark,
                            const float* __restrict__ hour_e, const float* __restrict__ wk_e,
                            const float* __restrict__ day_e, const float* __restrict__ mon_e,
                            const float* __restrict__ W_val, const float* __restrict__ b_val,
                            const float* __restrict__ b1, const float* __restrict__ b2,
                            const float* __restrict__ b3, const float* __restrict__ gbi,
                            const float* __restrict__ out) {
    __shared__ float buf[20*CSTR];     // 10,560 B
    __shared__ float wbuf[16*GDIM];    // 24,576 B (also holds 5440-float conv chunks)
    const int tid = threadIdx.x;
    const int b = blockIdx.x;
    const int gy = blockIdx.y;
    const int wbase = gy ? 83 : -6;    // emb row q <-> window row w = wbase + q

    // ---- embedding: 20 rows
    for (int e = tid; e < 20*DM; e += 256) {
        int q = e >> 7, d = e & 127;
        int w = wbase + q;
        float v = 0.f;
        if (w >= 0 && w < SEQ) {
            int p = i + w;
            const float* xr = (p < SEQ) ? (x_enc + (b*SEQ + p)*CIN)
                                        : (out + (b*PRED + (p - SEQ))*CIN);
            v = b_val[d];
            #pragma unroll
            for (int c = 0; c < CIN; ++c) v = fmaf(xr[c], W_val[d*CIN + c], v);
            const int* ym = y_mark + (b*TOT + p)*4;
            v += hour_e[ym[0]*DM + d] + wk_e[ym[1]*DM + d]
               + day_e[ym[2]*DM + d] + mon_e[ym[3]*DM + d];
        }
        buf[q*CSTR + d] = v;
    }
    // (step_layer starts with __syncthreads)
    step_layer(buf, wbuf, g_wT,            b1, 16, wbase + 2, tid);  // c1: 16 rows
    step_layer(buf, wbuf, g_wT + W_CONV,   b2, 12, wbase + 4, tid);  // c2: 12 rows
    step_layer(buf, wbuf, g_wT + 2*W_CONV, b3,  8, wbase + 6, tid);  // c3:  8 rows

    // ---- gx for the 8 c3 rows; thread: row = tid>>5, 12 g's
    const int row = tid >> 5;
    const int g0 = (tid & 31) * 12;
    const float* WiT = g_wT + OFF_WIT;
    float ga[12];
    #pragma unroll
    for (int e = 0; e < 12; ++e) ga[e] = gbi[g0+e];
    for (int cc = 0; cc < 8; ++cc) {
        __syncthreads();
        #pragma unroll
        for (int s = 0; s < 6; ++s)   // stage WiT rows cc*16..+15 (6144 floats)
            ((float4*)wbuf)[s*256 + tid] = ((const float4*)(WiT + cc*16*GDIM))[s*256 + tid];
        __syncthreads();
        #pragma unroll
        for (int c = 0; c < 16; ++c) {
            float a = buf[row*CSTR + cc*16 + c];
            float4 w0 = *(const float4*)(wbuf + c*GDIM + g0);
            float4 w1 = *(const float4*)(wbuf + c*GDIM + g0 + 4);
            float4 w2 = *(const float4*)(wbuf + c*GDIM + g0 + 8);
            ga[0]  = fmaf(a, w0.x, ga[0]);
            ga[1]  = fmaf(a, w0.y, ga[1]);
            ga[2]  = fmaf(a, w0.z, ga[2]);
            ga[3]  = fmaf(a, w0.w, ga[3]);
            ga[4]  = fmaf(a, w1.x, ga[4]);
            ga[5]  = fmaf(a, w1.y, ga[5]);
            ga[6]  = fmaf(a, w1.z, ga[6]);
            ga[7]  = fmaf(a, w1.w, ga[7]);
            ga[8]  = fmaf(a, w2.x, ga[8]);
            ga[9]  = fmaf(a, w2.y, ga[9]);
            ga[10] = fmaf(a, w2.z, ga[10]);
            ga[11] = fmaf(a, w2.w, ga[11]);
        }
    }
    // ---- store: left -> gxe[0..5]; right -> gxg[i+89] (row 0), gxe[6..11]
    const int w = wbase + 6 + row;
    float* dst = nullptr;
    if (gy == 0) {
        if (w < 6) dst = g_gxe + ((size_t)b*12 + w)*GDIM + g0;
    } else {
        if (w == 89)      dst = g_gxg + ((size_t)b*TOT + (i + 89))*GDIM + g0;
        else if (w < SEQ) dst = g_gxe + ((size_t)b*12 + (w - 84))*GDIM + g0;
    }
    if (dst) {
        #pragma unroll
        for (int q = 0; q < 3; ++q)
            *(float4*)(dst + q*4) = *(const float4*)&ga[q*4];
    }
}

// -------------------------------------------------------------- recurrence
// grid 512 (one batch row per block), 384 threads (thread = gate g).
__launch_bounds__(GDIM, 3)
__global__ void gru_rec(int i, const float* __restrict__ gbh,
                        const float* __restrict__ fc_w, const float* __restrict__ fc_b,
                        float* __restrict__ out) {
    __shared__ float H[DM];
    __shared__ float GS[2*DM];
    const int tid = threadIdx.x;
    const int b = blockIdx.x;
    const float* WhT = g_wT + OFF_WHT;

    float wh[DM];
    #pragma unroll
    for (int c = 0; c < DM; ++c) wh[c] = WhT[c*GDIM + tid];
    const float tbh = gbh[tid];

    if (tid < DM) H[tid] = 0.f;
    __syncthreads();

    const int lane = tid & 63;
    const int G = tid >> 7, jj = tid & 127;
    const float* gxg_b = g_gxg + (size_t)b*TOT*GDIM;
    const float* gxe_b = g_gxe + (size_t)b*12*GDIM;

    for (int t = 0; t < SEQ; ++t) {
        const float* gp = (t < 6)  ? (gxe_b + t*GDIM)
                        : (t < 90) ? (gxg_b + (size_t)(i + t)*GDIM)
                                   : (gxe_b + (t - 84)*GDIM);
        float gxt = gp[tid];                      // includes bi; independent of H
        float hv0 = H[lane], hv1 = H[64+lane];
        float a0 = tbh, a1 = 0.f, a2 = 0.f, a3 = 0.f;
        #pragma unroll
        for (int c = 0; c < 32; ++c) {
            a0 = fmaf(__int_as_float(__builtin_amdgcn_readlane(__float_as_int(hv0), c)),
                      wh[c], a0);
            a1 = fmaf(__int_as_float(__builtin_amdgcn_readlane(__float_as_int(hv0), c+32)),
                      wh[32+c], a1);
            a2 = fmaf(__int_as_float(__builtin_amdgcn_readlane(__float_as_int(hv1), c)),
                      wh[64+c], a2);
            a3 = fmaf(__int_as_float(__builtin_amdgcn_readlane(__float_as_int(hv1), c+32)),
                      wh[96+c], a3);
        }
        float gh = (a0 + a1) + (a2 + a3);         // includes bh
        if (G == 0)      GS[jj]      = 1.f/(1.f + __expf(-(gxt + gh)));  // r
        else if (G == 1) GS[DM + jj] = 1.f/(1.f + __expf(-(gxt + gh)));  // z
        __syncthreads();
        if (G == 2) {
            float r = GS[jj], z = GS[DM + jj];
            float n = tanhf(gxt + r*gh);
            H[jj] = (1.f - z)*n + z*H[jj];
        }
        __syncthreads();
    }

    if (tid < CIN) {
        float p = fc_b[tid];
        #pragma unroll
        for (int d = 0; d < DM; ++d) p = fmaf(fc_w[tid*DM + d], H[d], p);
        out[(b*PRED + i)*CIN + tid] = p;
    }
}

// ---------------------------------------------------------------- launch
extern "C" void kernel_launch(void* const* d_in, const int* in_sizes, int n_in,
                              void* d_out, int out_size, void* d_ws, size_t ws_size,
                              hipStream_t stream) {
    const float* x_enc  = (const float*)d_in[0];
    const int*   y_mark = (const int*)d_in[2];
    const float* hour_e = (const float*)d_in[3];
    const float* wk_e   = (const float*)d_in[4];
    const float* day_e  = (const float*)d_in[5];
    const float* mon_e  = (const float*)d_in[6];
    const float* W_val  = (const float*)d_in[7];
    const float* b_val  = (const float*)d_in[8];
    const float* c1w    = (const float*)d_in[9];
    const float* c1b    = (const float*)d_in[10];
    const float* c2w    = (const float*)d_in[11];
    const float* c2b    = (const float*)d_in[12];
    const float* c3w    = (const float*)d_in[13];
    const float* c3b    = (const float*)d_in[14];
    const float* Wi     = (const float*)d_in[15];
    const float* Wh     = (const float*)d_in[16];
    const float* gbi    = (const float*)d_in[17];
    const float* gbh    = (const float*)d_in[18];
    const float* fcw    = (const float*)d_in[19];
    const float* fcb    = (const float*)d_in[20];
    float* out = (float*)d_out;

    prep_weights<<<(W_TOTAL + 255)/256, 256, 0, stream>>>(c1w, c2w, c3w, Wi, Wh);

    init_kernel<<<dim3(B_SZ, 2), 256, 0, stream>>>(x_enc, y_mark,
        hour_e, wk_e, day_e, mon_e, W_val, b_val, c1b, c2b, c3b, gbi);

    for (int i = 0; i < PRED; ++i) {
        step_kernel<<<dim3(B_SZ, 2), 256, 0, stream>>>(i, x_enc, y_mark,
            hour_e, wk_e, day_e, mon_e, W_val, b_val, c1b, c2b, c3b, gbi, out);
        gru_rec<<<B_SZ, GDIM, 0, stream>>>(i, gbh, fcw, fcb, out);
    }
}

// Round 5
// 15817.056 us; speedup vs baseline: 2.4888x; 1.2562x over previous
//
#include <hip/hip_runtime.h>

#define B_SZ 512
#define SEQ 96
#define PRED 48
#define TOT 144
#define CIN 7
#define DM 128
#define GDIM 384
#define KS 5

#define CSTR 132              // LDS row stride for activation buffers
#define ASUB (20*CSTR)        // floats per 20-row sub-buffer
#define WROW 136              // swizzled LDS weight row (128 + pad)
#define SWZ(o) ((o) + ((((o) >> 6)) << 2))   // bank swizzle: pad 4 every 64 floats

#define W_CONV (KS*DM*DM)            // 81920 per conv layer (layout [k][c][o])
#define OFF_WIT (3*W_CONV)           // WiT [c][384]
#define OFF_WHT (3*W_CONV + DM*GDIM) // WhT [c][384]
#define W_TOTAL (3*W_CONV + 2*DM*GDIM)

// Device-global scratch
__device__ float g_gxg[(size_t)B_SZ*TOT*GDIM];  // invariant gx cache, [b][p][384]
__device__ float g_gxe[B_SZ*12*GDIM];           // per-step edge gx, [b][12][384]
__device__ float g_wT[W_TOTAL];                 // transposed weights

// ---------------------------------------------------------------- prep
__global__ void prep_weights(const float* __restrict__ w1, const float* __restrict__ w2,
                             const float* __restrict__ w3, const float* __restrict__ Wi,
                             const float* __restrict__ Wh) {
    int tid = blockIdx.x*256 + threadIdx.x;
    if (tid < 3*W_CONV) {
        int l = tid / W_CONV, r = tid % W_CONV;
        int o = r & 127, c = (r >> 7) & 127, k = r >> 14;   // r = (k*128+c)*128+o
        const float* w = (l==0) ? w1 : ((l==1) ? w2 : w3);
        g_wT[tid] = w[o*(DM*KS) + c*KS + k];                 // src [o][c][k]
    } else if (tid < W_TOTAL) {
        int r = tid - 3*W_CONV;
        int m = r / (DM*GDIM), q = r % (DM*GDIM);
        int g = q % GDIM, c = q / GDIM;                      // dst [c][g]
        const float* W = (m==0) ? Wi : Wh;
        g_wT[tid] = W[g*DM + c];                             // src [g][c]
    }
}

// ---------------------------------------------------------------- fma helper
template<int NJ>
__device__ __forceinline__ void fma8(float (&acc)[NJ][8], int j, float a,
                                     const float4& wA, const float4& wB) {
    acc[j][0] = fmaf(a, wA.x, acc[j][0]);
    acc[j][1] = fmaf(a, wA.y, acc[j][1]);
    acc[j][2] = fmaf(a, wA.z, acc[j][2]);
    acc[j][3] = fmaf(a, wA.w, acc[j][3]);
    acc[j][4] = fmaf(a, wB.x, acc[j][4]);
    acc[j][5] = fmaf(a, wB.y, acc[j][5]);
    acc[j][6] = fmaf(a, wB.z, acc[j][6]);
    acc[j][7] = fmaf(a, wB.w, acc[j][7]);
}

// stage 8 channels of conv weights (swizzled) into wbuf — 256-thread version (init)
__device__ __forceinline__ void stage_conv_chunk(float* __restrict__ wbuf,
                                                 const float* __restrict__ wT,
                                                 int cc, int tid) {
    const int cj = tid >> 5, oo = (tid & 31) * 4;
    #pragma unroll
    for (int k = 0; k < KS; ++k)
        *(float4*)(wbuf + (k*8 + cj)*WROW + SWZ(oo)) =
            *(const float4*)(wT + (k*DM + cc*8 + cj)*DM + oo);
}

// Chunked in-place conv layer (init kernel, 256 threads).
template<int NJ>
__device__ __forceinline__ void conv_layer_chunked(float* __restrict__ buf,
                                                   float* __restrict__ wbuf,
                                                   const float* __restrict__ wT,
                                                   const float* __restrict__ bias,
                                                   int nrow, int winO, int tid) {
    const int og = tid & 15, ttg = tid >> 4;
    const int o0 = og*8, so0 = SWZ(o0), r0 = ttg*NJ;
    const bool act = (r0 < nrow);
    float acc[NJ][8];
    #pragma unroll
    for (int u = 0; u < 8; ++u) {
        float bv = bias[o0+u];
        #pragma unroll
        for (int j = 0; j < NJ; ++j) acc[j][u] = bv;
    }
    for (int cc = 0; cc < DM/8; ++cc) {
        __syncthreads();
        stage_conv_chunk(wbuf, wT, cc, tid);
        __syncthreads();
        if (act) {
            const int c0 = cc*8;
            #pragma unroll
            for (int cj = 0; cj < 8; cj += 2) {
                float2 a2[NJ+4];
                #pragma unroll
                for (int m = 0; m < NJ+4; ++m)
                    a2[m] = *(const float2*)(buf + (r0+m)*CSTR + c0 + cj);
                #pragma unroll
                for (int k = 0; k < KS; ++k) {
                    const float4 wA0 = *(const float4*)(wbuf + (k*8+cj)*WROW + so0);
                    const float4 wB0 = *(const float4*)(wbuf + (k*8+cj)*WROW + so0 + 4);
                    const float4 wA1 = *(const float4*)(wbuf + (k*8+cj+1)*WROW + so0);
                    const float4 wB1 = *(const float4*)(wbuf + (k*8+cj+1)*WROW + so0 + 4);
                    #pragma unroll
                    for (int j = 0; j < NJ; ++j) {
                        fma8(acc, j, a2[j+k].x, wA0, wB0);
                        fma8(acc, j, a2[j+k].y, wA1, wB1);
                    }
                }
            }
        }
    }
    __syncthreads();
    if (act) {
        #pragma unroll
        for (int j = 0; j < NJ; ++j) {
            int q = r0 + j, w = winO + q;
            bool valid = (w >= 0) && (w < SEQ);
            #pragma unroll
            for (int u = 0; u < 8; ++u)
                buf[q*CSTR + o0+u] = valid ? fmaxf(acc[j][u], 0.f) : 0.f;
        }
    }
    __syncthreads();
}

// ------------------------------------------------------------- init kernel
// Step 0's full conv cascade; stores invariant gx rows w in [6,90) to g_gxg[b][w].
__launch_bounds__(256, 3)
__global__ void init_kernel(const float* __restrict__ x_enc,
                            const int* __restrict__ y_mark,
                            const float* __restrict__ hour_e, const float* __restrict__ wk_e,
                            const float* __restrict__ day_e, const float* __restrict__ mon_e,
                            const float* __restrict__ W_val, const float* __restrict__ b_val,
                            const float* __restrict__ b1, const float* __restrict__ b2,
                            const float* __restrict__ b3, const float* __restrict__ gbi) {
    __shared__ float buf[60*CSTR];
    __shared__ float wbuf[KS*8*WROW];
    const int tid = threadIdx.x;
    const int b = blockIdx.x;
    const int cs = blockIdx.y * 48;

    for (int e = tid; e < 60*DM; e += 256) {
        int q = e >> 7, d = e & 127;
        int w = cs - 6 + q;
        float v = 0.f;
        if (w >= 0 && w < SEQ) {
            const float* xr = x_enc + (b*SEQ + w)*CIN;
            v = b_val[d];
            #pragma unroll
            for (int c = 0; c < CIN; ++c) v = fmaf(xr[c], W_val[d*CIN + c], v);
            const int* ym = y_mark + (b*TOT + w)*4;
            v += hour_e[ym[0]*DM + d] + wk_e[ym[1]*DM + d]
               + day_e[ym[2]*DM + d] + mon_e[ym[3]*DM + d];
        }
        buf[q*CSTR + d] = v;
    }
    conv_layer_chunked<4>(buf, wbuf, g_wT,            b1, 56, cs - 4, tid);
    conv_layer_chunked<4>(buf, wbuf, g_wT + W_CONV,   b2, 52, cs - 2, tid);
    conv_layer_chunked<3>(buf, wbuf, g_wT + 2*W_CONV, b3, 48, cs,     tid);

    const int og = tid & 15, ttg = tid >> 4;
    const int g0 = og*24, r0 = ttg*3;
    const float* WiT = g_wT + OFF_WIT;
    float ga[3][24];
    #pragma unroll
    for (int e = 0; e < 24; ++e) {
        float bv = gbi[g0+e];
        #pragma unroll
        for (int j = 0; j < 3; ++j) ga[j][e] = bv;
    }
    for (int cc = 0; cc < DM/8; ++cc) {
        __syncthreads();
        #pragma unroll
        for (int s = 0; s < 3; ++s)
            ((float4*)wbuf)[s*256 + tid] = ((const float4*)(WiT + cc*8*GDIM))[s*256 + tid];
        __syncthreads();
        const int c0 = cc*8;
        #pragma unroll
        for (int cj = 0; cj < 8; cj += 2) {
            float2 a2[3];
            #pragma unroll
            for (int m = 0; m < 3; ++m)
                a2[m] = *(const float2*)(buf + (r0+m)*CSTR + c0 + cj);
            float4 w4[6];
            #pragma unroll
            for (int q = 0; q < 6; ++q)
                w4[q] = *(const float4*)(wbuf + cj*GDIM + g0 + q*4);
            const float* wv = (const float*)w4;
            #pragma unroll
            for (int j = 0; j < 3; ++j)
                #pragma unroll
                for (int e = 0; e < 24; ++e)
                    ga[j][e] = fmaf(a2[j].x, wv[e], ga[j][e]);
            #pragma unroll
            for (int q = 0; q < 6; ++q)
                w4[q] = *(const float4*)(wbuf + (cj+1)*GDIM + g0 + q*4);
            #pragma unroll
            for (int j = 0; j < 3; ++j)
                #pragma unroll
                for (int e = 0; e < 24; ++e)
                    ga[j][e] = fmaf(a2[j].y, wv[e], ga[j][e]);
        }
    }
    #pragma unroll
    for (int j = 0; j < 3; ++j) {
        int w = cs + r0 + j;
        if (w >= 6 && w < 90) {
            float* gxo = g_gxg + ((size_t)b*TOT + w)*GDIM + g0;
            #pragma unroll
            for (int q = 0; q < 6; ++q)
                *(float4*)(gxo + q*4) = *(const float4*)&ga[j][q*4];
        }
    }
}

// ------------------------------------------------------------- merged step layer
// 512 threads, 4 sub-buffers (2 batches x 2 edges). R rows/sub, NJ rows/thread.
template<int NJ>
__device__ __forceinline__ void mlayer(float* __restrict__ abuf, float* __restrict__ wbuf,
                                       const float* __restrict__ wT,
                                       const float* __restrict__ bias,
                                       int R, int off, int tid) {
    const int og = tid & 15, ttg = tid >> 4;     // og 0..15, ttg 0..31
    const int o0 = og*8, so0 = SWZ(o0);
    const int m0 = ttg * NJ;
    const bool act = (m0 < 4*R);
    int s = 0, r0 = 0;
    if (act) { s = m0 / R; r0 = m0 - s*R; }      // NJ divides R -> rows don't span subs
    float* in = abuf + s*ASUB;
    float acc[NJ][8];
    #pragma unroll
    for (int u = 0; u < 8; ++u) {
        float bv = bias[o0+u];
        #pragma unroll
        for (int j = 0; j < NJ; ++j) acc[j][u] = bv;
    }
    for (int cc = 0; cc < DM/8; ++cc) {
        __syncthreads();
        for (int x = tid; x < 1280; x += 512) {   // 5 k x 8 c x 32 float4
            int k = x >> 8, rr = (x >> 5) & 7, oo = (x & 31)*4;
            *(float4*)(wbuf + (k*8+rr)*WROW + SWZ(oo)) =
                *(const float4*)(wT + (k*DM + cc*8 + rr)*DM + oo);
        }
        __syncthreads();
        if (act) {
            const int c0 = cc*8;
            #pragma unroll
            for (int cj = 0; cj < 8; cj += 2) {
                float2 a2[NJ+4];
                #pragma unroll
                for (int m = 0; m < NJ+4; ++m)
                    a2[m] = *(const float2*)(in + (r0+m)*CSTR + c0 + cj);
                #pragma unroll
                for (int k = 0; k < KS; ++k) {
                    const float4 wA0 = *(const float4*)(wbuf + (k*8+cj)*WROW + so0);
                    const float4 wB0 = *(const float4*)(wbuf + (k*8+cj)*WROW + so0 + 4);
                    const float4 wA1 = *(const float4*)(wbuf + (k*8+cj+1)*WROW + so0);
                    const float4 wB1 = *(const float4*)(wbuf + (k*8+cj+1)*WROW + so0 + 4);
                    #pragma unroll
                    for (int j = 0; j < NJ; ++j) {
                        fma8(acc, j, a2[j+k].x, wA0, wB0);
                        fma8(acc, j, a2[j+k].y, wA1, wB1);
                    }
                }
            }
        }
    }
    __syncthreads();
    if (act) {
        const int wb = (s & 1) ? 83 : -6;
        #pragma unroll
        for (int j = 0; j < NJ; ++j) {
            int q = r0 + j, w = wb + off + q;
            bool valid = (w >= 0) && (w < SEQ);
            #pragma unroll
            for (int u = 0; u < 8; ++u)
                in[q*CSTR + o0+u] = valid ? fmaxf(acc[j][u], 0.f) : 0.f;
        }
    }
    __syncthreads();
}

// ------------------------------------------------------------- step kernel
// grid 256, 512 threads. Block handles batches b0,b0+1 x both edges (4 subs).
__launch_bounds__(512, 2)
__global__ void step_kernel(int i, const float* __restrict__ x_enc,
                            const int* __restrict__ y_mark,
                            const float* __restrict__ hour_e, const float* __restrict__ wk_e,
                            const float* __restrict__ day_e, const float* __restrict__ mon_e,
                            const float* __restrict__ W_val, const float* __restrict__ b_val,
                            const float* __restrict__ b1, const float* __restrict__ b2,
                            const float* __restrict__ b3, const float* __restrict__ gbi,
                            const float* __restrict__ out) {
    __shared__ float abuf[4*ASUB];     // 42.24 KB
    __shared__ float wbuf[16*GDIM];    // 24.58 KB (conv chunks use 5440 floats of it)
    const int tid = threadIdx.x;
    const int b0 = blockIdx.x * 2;

    // ---- embedding: 4 subs x 20 rows x 128
    for (int e = tid; e < 4*20*DM; e += 512) {
        int s = e / (20*DM);
        int rem = e - s*(20*DM);
        int q = rem >> 7, d = rem & 127;
        int wb = (s & 1) ? 83 : -6;
        int b = b0 + (s >> 1);
        int w = wb + q;
        float v = 0.f;
        if (w >= 0 && w < SEQ) {
            int p = i + w;
            const float* xr = (p < SEQ) ? (x_enc + (b*SEQ + p)*CIN)
                                        : (out + (b*PRED + (p - SEQ))*CIN);
            v = b_val[d];
            #pragma unroll
            for (int c = 0; c < CIN; ++c) v = fmaf(xr[c], W_val[d*CIN + c], v);
            const int* ym = y_mark + (b*TOT + p)*4;
            v += hour_e[ym[0]*DM + d] + wk_e[ym[1]*DM + d]
               + day_e[ym[2]*DM + d] + mon_e[ym[3]*DM + d];
        }
        abuf[s*ASUB + q*CSTR + d] = v;
    }
    mlayer<2>(abuf, wbuf, g_wT,            b1, 16, 2, tid);  // c1: 64 rows
    mlayer<2>(abuf, wbuf, g_wT + W_CONV,   b2, 12, 4, tid);  // c2: 48 rows
    mlayer<1>(abuf, wbuf, g_wT + 2*W_CONV, b3,  8, 6, tid);  // c3: 32 rows

    // ---- gx: 32 c3 rows; thread tile = 2 rows x 12 g
    const int mp = tid >> 5;                 // 0..15 row-pairs
    const int g0 = (tid & 31) * 12;
    const int s = mp >> 2;                   // sub-buffer (2 rows same sub)
    const int row0 = (2*mp) & 7;
    const float* a0p = abuf + s*ASUB + row0*CSTR;
    const float* a1p = a0p + CSTR;
    const float* WiT = g_wT + OFF_WIT;
    float ga[2][12];
    #pragma unroll
    for (int e = 0; e < 12; ++e) { float bv = gbi[g0+e]; ga[0][e] = bv; ga[1][e] = bv; }
    for (int cc = 0; cc < 8; ++cc) {
        __syncthreads();
        for (int x = tid; x < 16*GDIM/4; x += 512)
            ((float4*)wbuf)[x] = ((const float4*)(WiT + cc*16*GDIM))[x];
        __syncthreads();
        #pragma unroll
        for (int c = 0; c < 16; ++c) {
            float av0 = a0p[cc*16 + c];
            float av1 = a1p[cc*16 + c];
            const float* wr = wbuf + c*GDIM + g0;
            #pragma unroll
            for (int q4 = 0; q4 < 3; ++q4) {
                float4 w4 = *(const float4*)(wr + q4*4);
                ga[0][q4*4+0] = fmaf(av0, w4.x, ga[0][q4*4+0]);
                ga[0][q4*4+1] = fmaf(av0, w4.y, ga[0][q4*4+1]);
                ga[0][q4*4+2] = fmaf(av0, w4.z, ga[0][q4*4+2]);
                ga[0][q4*4+3] = fmaf(av0, w4.w, ga[0][q4*4+3]);
                ga[1][q4*4+0] = fmaf(av1, w4.x, ga[1][q4*4+0]);
                ga[1][q4*4+1] = fmaf(av1, w4.y, ga[1][q4*4+1]);
                ga[1][q4*4+2] = fmaf(av1, w4.z, ga[1][q4*4+2]);
                ga[1][q4*4+3] = fmaf(av1, w4.w, ga[1][q4*4+3]);
            }
        }
    }
    const int wb = (s & 1) ? 83 : -6;
    const int b = b0 + (s >> 1);
    #pragma unroll
    for (int j = 0; j < 2; ++j) {
        int w = wb + 6 + row0 + j;
        float* dst = nullptr;
        if (!(s & 1)) {
            if (w < 6) dst = g_gxe + ((size_t)b*12 + w)*GDIM + g0;
        } else {
            if (w == 89)      dst = g_gxg + ((size_t)b*TOT + (i + 89))*GDIM + g0;
            else if (w < SEQ) dst = g_gxe + ((size_t)b*12 + (w - 84))*GDIM + g0;
        }
        if (dst) {
            *(float4*)(dst)     = *(const float4*)&ga[j][0];
            *(float4*)(dst + 4) = *(const float4*)&ga[j][4];
            *(float4*)(dst + 8) = *(const float4*)&ga[j][8];
        }
    }
}

// -------------------------------------------------------------- recurrence
// grid 512 (one batch row per block), 384 threads (thread = gate g).
// Dot via LDS-broadcast float4 reads of H (no readlane/SGPR hazards).
__launch_bounds__(GDIM, 3)
__global__ void gru_rec(int i, const float* __restrict__ gbh,
                        const float* __restrict__ fc_w, const float* __restrict__ fc_b,
                        float* __restrict__ out) {
    __shared__ __align__(16) float H[DM];
    __shared__ float GS[2*DM];
    const int tid = threadIdx.x;
    const int b = blockIdx.x;
    const float* WhT = g_wT + OFF_WHT;

    float wh[DM];
    #pragma unroll
    for (int c = 0; c < DM; ++c) wh[c] = WhT[c*GDIM + tid];
    const float tbh = gbh[tid];

    if (tid < DM) H[tid] = 0.f;
    __syncthreads();

    const int G = tid >> 7, jj = tid & 127;
    const float* gxg_b = g_gxg + (size_t)b*TOT*GDIM;
    const float* gxe_b = g_gxe + (size_t)b*12*GDIM;

    // t -> gx row pointer (edge rows from gxe, interior from position cache)
    auto gp = [&](int t) -> const float* {
        return (t < 6)  ? (gxe_b + t*GDIM)
             : (t < 90) ? (gxg_b + (size_t)(i + t)*GDIM)
                        : (gxe_b + (t - 84)*GDIM);
    };

    float gxt = gp(0)[tid];
    for (int t = 0; t < SEQ; ++t) {
        float gxn = (t + 1 < SEQ) ? gp(t + 1)[tid] : 0.f;   // prefetch next t
        float a0 = tbh, a1 = 0.f, a2 = 0.f, a3 = 0.f;
        #pragma unroll
        for (int c = 0; c < DM; c += 4) {
            float4 h4 = *(const float4*)(H + c);   // wave-uniform -> LDS broadcast
            a0 = fmaf(h4.x, wh[c],   a0);
            a1 = fmaf(h4.y, wh[c+1], a1);
            a2 = fmaf(h4.z, wh[c+2], a2);
            a3 = fmaf(h4.w, wh[c+3], a3);
        }
        float gh = (a0 + a1) + (a2 + a3);          // includes bh
        float x = gxt + gh;
        if (G == 0)      GS[jj]      = 1.f/(1.f + __expf(-x));   // r
        else if (G == 1) GS[DM + jj] = 1.f/(1.f + __expf(-x));   // z
        __syncthreads();
        if (G == 2) {
            float r = GS[jj], z = GS[DM + jj];
            float xn = gxt + r*gh;
            float e2 = __expf(2.f*xn);
            float n = 1.f - 2.f/(e2 + 1.f);        // tanh(xn)
            H[jj] = (1.f - z)*n + z*H[jj];
        }
        __syncthreads();
        gxt = gxn;
    }

    if (tid < CIN) {
        float p = fc_b[tid];
        #pragma unroll
        for (int d = 0; d < DM; ++d) p = fmaf(fc_w[tid*DM + d], H[d], p);
        out[(b*PRED + i)*CIN + tid] = p;
    }
}

// ---------------------------------------------------------------- launch
extern "C" void kernel_launch(void* const* d_in, const int* in_sizes, int n_in,
                              void* d_out, int out_size, void* d_ws, size_t ws_size,
                              hipStream_t stream) {
    const float* x_enc  = (const float*)d_in[0];
    const int*   y_mark = (const int*)d_in[2];
    const float* hour_e = (const float*)d_in[3];
    const float* wk_e   = (const float*)d_in[4];
    const float* day_e  = (const float*)d_in[5];
    const float* mon_e  = (const float*)d_in[6];
    const float* W_val  = (const float*)d_in[7];
    const float* b_val  = (const float*)d_in[8];
    const float* c1w    = (const float*)d_in[9];
    const float* c1b    = (const float*)d_in[10];
    const float* c2w    = (const float*)d_in[11];
    const float* c2b    = (const float*)d_in[12];
    const float* c3w    = (const float*)d_in[13];
    const float* c3b    = (const float*)d_in[14];
    const float* Wi     = (const float*)d_in[15];
    const float* Wh     = (const float*)d_in[16];
    const float* gbi    = (const float*)d_in[17];
    const float* gbh    = (const float*)d_in[18];
    const float* fcw    = (const float*)d_in[19];
    const float* fcb    = (const float*)d_in[20];
    float* out = (float*)d_out;

    prep_weights<<<(W_TOTAL + 255)/256, 256, 0, stream>>>(c1w, c2w, c3w, Wi, Wh);

    init_kernel<<<dim3(B_SZ, 2), 256, 0, stream>>>(x_enc, y_mark,
        hour_e, wk_e, day_e, mon_e, W_val, b_val, c1b, c2b, c3b, gbi);

    for (int i = 0; i < PRED; ++i) {
        step_kernel<<<B_SZ/2, 512, 0, stream>>>(i, x_enc, y_mark,
            hour_e, wk_e, day_e, mon_e, W_val, b_val, c1b, c2b, c3b, gbi, out);
        gru_rec<<<B_SZ, GDIM, 0, stream>>>(i, gbh, fcw, fcb, out);
    }
}